// Round 6
// baseline (224.051 us; speedup 1.0000x reference)
//
#include <hip/hip_runtime.h>

// GATConv forward on MI355X — round 6.
// vs r5: (1) edge weights stored as 4 head-planes wT[hd][edge] -> gather
// reads w as float4 per 4 edges and srcs as int4 per 4 edges (fewer VMEM
// issues); (2) gather unrolled x8 with 4 independent accumulator chains;
// (3) scan_blk fused into add_off (one fewer launch).

#define NN 50000      // nodes
#define NE 800000     // real edges
#define ET 850000     // edges + self loops
#define WP 850048     // padded plane stride for wT
#define KF 256        // IN_F
#define HF 256        // HEADS*OUT_F
#define HROW 512      // bytes per hb row (256 * bf16)

typedef __attribute__((ext_vector_type(8))) short bf16x8;
typedef __attribute__((ext_vector_type(4))) float f32x4;

static __device__ __forceinline__ unsigned short f2bf(float f) {
    unsigned u = __builtin_bit_cast(unsigned, f);
    u += 0x7fffu + ((u >> 16) & 1u);            // round-to-nearest-even
    return (unsigned short)(u >> 16);
}
static __device__ __forceinline__ float bf2f(unsigned short s) {
    return __builtin_bit_cast(float, ((unsigned)s) << 16);
}

// ------------- prep: transpose W (blocks 0..255) + count edges (rest) -------
__global__ __launch_bounds__(256) void prep(
    const float* __restrict__ W, unsigned short* __restrict__ WbT,
    const int* __restrict__ ei, int* __restrict__ cnt)
{
    const int b = blockIdx.x;
    if (b < 256) {
        int g = b * 256 + threadIdx.x;
        int n = g >> 8, k = g & 255;
        WbT[n * 256 + k] = f2bf(W[k * 256 + n]);
    } else {
        int e = (b - 256) * 256 + threadIdx.x;
        if (e < ET) {
            int d = (e < NE) ? ei[NE + e] : e - NE;
            atomicAdd(&cnt[d], 1);
        }
    }
}

// ------------- GEMM + fused attention dots ----------------------------------
__global__ __launch_bounds__(256) void gemm_mfma(
    const float* __restrict__ x, const unsigned short* __restrict__ WbT,
    const float* __restrict__ att_s, const float* __restrict__ att_d,
    unsigned short* __restrict__ hb, float* __restrict__ a_src,
    float* __restrict__ a_dst)
{
    __shared__ unsigned short As[64 * 256];      // [row][k], 16B slots XOR-swizzled
    const int tid  = threadIdx.x;
    const int row0 = blockIdx.x * 64;
    {
        const int row = tid >> 2, s = tid & 3;
        const int grow = row0 + row;
        #pragma unroll
        for (int kc = 0; kc < 8; ++kc) {
            int slot = kc * 4 + s;               // 16B slot (k = slot*8..+7)
            float4 p = make_float4(0.f,0.f,0.f,0.f), q = p;
            if (grow < NN) {
                const float* src = &x[(size_t)grow * KF + slot * 8];
                p = *(const float4*)src;
                q = *(const float4*)(src + 4);
            }
            bf16x8 v;
            v[0]=(short)f2bf(p.x); v[1]=(short)f2bf(p.y);
            v[2]=(short)f2bf(p.z); v[3]=(short)f2bf(p.w);
            v[4]=(short)f2bf(q.x); v[5]=(short)f2bf(q.y);
            v[6]=(short)f2bf(q.z); v[7]=(short)f2bf(q.w);
            *(bf16x8*)&As[row * 256 + ((slot ^ (row & 7)) * 8)] = v;
        }
    }
    __syncthreads();

    const int wave = tid >> 6, lane = tid & 63;
    const int r = lane & 15, g = lane >> 4;
    const int c0 = wave * 64;
    f32x4 acc[4][4] = {};
    #pragma unroll 2
    for (int kstep = 0; kstep < 8; ++kstep) {
        const int k0 = kstep * 32;
        bf16x8 af[4], bfr[4];
        #pragma unroll
        for (int mf = 0; mf < 4; ++mf) {
            int arow = mf * 16 + r;
            int slot = (kstep * 4 + g) ^ (arow & 7);
            af[mf] = *(const bf16x8*)&As[arow * 256 + slot * 8];
        }
        #pragma unroll
        for (int nf = 0; nf < 4; ++nf) {
            int col = c0 + nf * 16 + r;
            bfr[nf] = *(const bf16x8*)&WbT[(size_t)col * 256 + k0 + g * 8];
        }
        #pragma unroll
        for (int mf = 0; mf < 4; ++mf)
            #pragma unroll
            for (int nf = 0; nf < 4; ++nf)
                acc[mf][nf] = __builtin_amdgcn_mfma_f32_16x16x32_bf16(
                    af[mf], bfr[nf], acc[mf][nf], 0, 0, 0);
    }
    // ---- fused attention epilogue (head == wave) ---------------------------
    {
        float as[4], ad[4];
        #pragma unroll
        for (int nf = 0; nf < 4; ++nf) {
            as[nf] = att_s[c0 + nf * 16 + r];
            ad[nf] = att_d[c0 + nf * 16 + r];
        }
        #pragma unroll
        for (int mf = 0; mf < 4; ++mf) {
            #pragma unroll
            for (int rr = 0; rr < 4; ++rr) {
                float ps = acc[mf][0][rr]*as[0] + acc[mf][1][rr]*as[1]
                         + acc[mf][2][rr]*as[2] + acc[mf][3][rr]*as[3];
                float pd = acc[mf][0][rr]*ad[0] + acc[mf][1][rr]*ad[1]
                         + acc[mf][2][rr]*ad[2] + acc[mf][3][rr]*ad[3];
                #pragma unroll
                for (int m = 1; m < 16; m <<= 1) {
                    ps += __shfl_xor(ps, m);
                    pd += __shfl_xor(pd, m);
                }
                if (r == 0) {
                    int orow = row0 + mf * 16 + g * 4 + rr;
                    if (orow < NN) {
                        a_src[orow * 4 + wave] = ps;
                        a_dst[orow * 4 + wave] = pd;
                    }
                }
            }
        }
    }
    // ---- hb store ----------------------------------------------------------
    #pragma unroll
    for (int mf = 0; mf < 4; ++mf) {
        #pragma unroll
        for (int rr = 0; rr < 4; ++rr) {
            int orow = row0 + mf * 16 + g * 4 + rr;
            if (orow < NN) {
                #pragma unroll
                for (int nf = 0; nf < 4; ++nf)
                    hb[(size_t)orow * HF + c0 + nf * 16 + r] = f2bf(acc[mf][nf][rr]);
            }
        }
    }
}

// ------------- hierarchical scan --------------------------------------------
__global__ __launch_bounds__(256) void scan_local(
    const int* __restrict__ cnt, int* __restrict__ off, int* __restrict__ blksum)
{
    __shared__ int part[256];
    const int t = threadIdx.x;
    const int base = blockIdx.x * 1024 + t * 4;
    int4 v = make_int4(0, 0, 0, 0);
    if (base < NN) v = *(const int4*)&cnt[base];
    int s0 = v.x, s1 = s0 + v.y, s2 = s1 + v.z, s3 = s2 + v.w;
    part[t] = s3;
    __syncthreads();
    #pragma unroll
    for (int ofs = 1; ofs < 256; ofs <<= 1) {
        int u = (t >= ofs) ? part[t - ofs] : 0;
        __syncthreads();
        part[t] += u;
        __syncthreads();
    }
    int excl = part[t] - s3;
    if (base < NN)
        *(int4*)&off[base] = make_int4(excl, excl + s0, excl + s1, excl + s2);
    if (t == 255) blksum[blockIdx.x] = part[255];
}

// fused: each block re-scans the 49 block sums in wave 0, then adds.
__global__ __launch_bounds__(256) void add_off(
    int* __restrict__ off, int* __restrict__ cur, const int* __restrict__ blksum)
{
    __shared__ int s_bo;
    if (threadIdx.x < 64) {
        int t = threadIdx.x;
        int v = (t < 49) ? blksum[t] : 0;
        int incl = v;
        #pragma unroll
        for (int d = 1; d < 64; d <<= 1) {
            int u = __shfl_up(incl, d);
            if (t >= d) incl += u;
        }
        if (t == (int)blockIdx.x) s_bo = incl - v;   // exclusive prefix
    }
    __syncthreads();
    const int bo = s_bo;
    const int base = blockIdx.x * 1024 + threadIdx.x * 4;
    if (base < NN) {
        int4 o = *(const int4*)&off[base];
        o.x += bo; o.y += bo; o.z += bo; o.w += bo;
        *(int4*)&off[base] = o;
        *(int4*)&cur[base] = o;
    }
    if (blockIdx.x == 0 && threadIdx.x == 0) off[NN] = ET;
}

// ------------- scatter: CSR order + per-edge exp weights (head planes) ------
__global__ __launch_bounds__(256) void scatter_edges(
    const int* __restrict__ ei, const float* __restrict__ a_src,
    const float* __restrict__ a_dst, int* __restrict__ cur,
    int* __restrict__ srcs, float* __restrict__ wT)
{
    int e = blockIdx.x * 256 + threadIdx.x;
    if (e >= ET) return;
    int s, d;
    if (e < NE) { s = ei[e]; d = ei[NE + e]; }
    else        { s = e - NE; d = s; }
    float4 av = *(const float4*)&a_src[s * 4];
    float4 bv = *(const float4*)&a_dst[d * 4];
    float4 ev;
    ev.x = av.x + bv.x; ev.y = av.y + bv.y;
    ev.z = av.z + bv.z; ev.w = av.w + bv.w;
    ev.x = ev.x > 0.f ? ev.x : 0.2f * ev.x;
    ev.y = ev.y > 0.f ? ev.y : 0.2f * ev.y;
    ev.z = ev.z > 0.f ? ev.z : 0.2f * ev.z;
    ev.w = ev.w > 0.f ? ev.w : 0.2f * ev.w;
    ev.x = __expf(ev.x); ev.y = __expf(ev.y);
    ev.z = __expf(ev.z); ev.w = __expf(ev.w);
    int pos = atomicAdd(&cur[d], 1);
    srcs[pos] = s * HROW;                        // byte offset into hb
    wT[pos]          = ev.x;
    wT[WP + pos]     = ev.y;
    wT[2 * WP + pos] = ev.z;
    wT[3 * WP + pos] = ev.w;
}

// ------------- gather aggregation: one wave per dst node --------------------
// out[n] = relu( (sum w_e * h[s_e]) / (sum w_e + eps) + bias )
__global__ __launch_bounds__(256) void gather_agg(
    const int* __restrict__ srcs, const float* __restrict__ wT,
    const int* __restrict__ off, const unsigned short* __restrict__ hb,
    const float* __restrict__ bias, float* __restrict__ out)
{
    int n    = (blockIdx.x * 256 + threadIdx.x) >> 6;
    int lane = threadIdx.x & 63;
    if (n >= NN) return;
    const int beg = off[n], end = off[n + 1];
    const int hd  = lane >> 4;
    const int f   = lane << 2;
    const float* wp = wT + (size_t)hd * WP;
    const char* hbase = (const char*)hb + (lane << 3);
    float4 a0 = make_float4(0.f,0.f,0.f,0.f), a1 = a0, a2 = a0, a3 = a0;
    float sw0 = 0.f, sw1 = 0.f, sw2 = 0.f, sw3 = 0.f;
    int k = beg;
    // align k to 4 for vector loads
    for (; k < end && (k & 3); ++k) {
        int so = srcs[k];
        float w = wp[k];
        ushort4 u = *(const ushort4*)(hbase + so);
        sw0 += w;
        a0.x += w * bf2f(u.x); a0.y += w * bf2f(u.y);
        a0.z += w * bf2f(u.z); a0.w += w * bf2f(u.w);
    }
    for (; k + 7 < end; k += 8) {
        int4 sA = *(const int4*)&srcs[k];
        int4 sB = *(const int4*)&srcs[k + 4];
        float4 wA = *(const float4*)&wp[k];
        float4 wB = *(const float4*)&wp[k + 4];
        ushort4 u0 = *(const ushort4*)(hbase + sA.x);
        ushort4 u1 = *(const ushort4*)(hbase + sA.y);
        ushort4 u2 = *(const ushort4*)(hbase + sA.z);
        ushort4 u3 = *(const ushort4*)(hbase + sA.w);
        ushort4 u4 = *(const ushort4*)(hbase + sB.x);
        ushort4 u5 = *(const ushort4*)(hbase + sB.y);
        ushort4 u6 = *(const ushort4*)(hbase + sB.z);
        ushort4 u7 = *(const ushort4*)(hbase + sB.w);
        sw0 += wA.x + wB.x; sw1 += wA.y + wB.y;
        sw2 += wA.z + wB.z; sw3 += wA.w + wB.w;
        a0.x += wA.x * bf2f(u0.x) + wB.x * bf2f(u4.x);
        a0.y += wA.x * bf2f(u0.y) + wB.x * bf2f(u4.y);
        a0.z += wA.x * bf2f(u0.z) + wB.x * bf2f(u4.z);
        a0.w += wA.x * bf2f(u0.w) + wB.x * bf2f(u4.w);
        a1.x += wA.y * bf2f(u1.x) + wB.y * bf2f(u5.x);
        a1.y += wA.y * bf2f(u1.y) + wB.y * bf2f(u5.y);
        a1.z += wA.y * bf2f(u1.z) + wB.y * bf2f(u5.z);
        a1.w += wA.y * bf2f(u1.w) + wB.y * bf2f(u5.w);
        a2.x += wA.z * bf2f(u2.x) + wB.z * bf2f(u6.x);
        a2.y += wA.z * bf2f(u2.y) + wB.z * bf2f(u6.y);
        a2.z += wA.z * bf2f(u2.z) + wB.z * bf2f(u6.z);
        a2.w += wA.z * bf2f(u2.w) + wB.z * bf2f(u6.w);
        a3.x += wA.w * bf2f(u3.x) + wB.w * bf2f(u7.x);
        a3.y += wA.w * bf2f(u3.y) + wB.w * bf2f(u7.y);
        a3.z += wA.w * bf2f(u3.z) + wB.w * bf2f(u7.z);
        a3.w += wA.w * bf2f(u3.w) + wB.w * bf2f(u7.w);
    }
    if (k + 3 < end) {
        int4 sA = *(const int4*)&srcs[k];
        float4 wA = *(const float4*)&wp[k];
        ushort4 u0 = *(const ushort4*)(hbase + sA.x);
        ushort4 u1 = *(const ushort4*)(hbase + sA.y);
        ushort4 u2 = *(const ushort4*)(hbase + sA.z);
        ushort4 u3 = *(const ushort4*)(hbase + sA.w);
        sw0 += wA.x; sw1 += wA.y; sw2 += wA.z; sw3 += wA.w;
        a0.x += wA.x * bf2f(u0.x); a0.y += wA.x * bf2f(u0.y);
        a0.z += wA.x * bf2f(u0.z); a0.w += wA.x * bf2f(u0.w);
        a1.x += wA.y * bf2f(u1.x); a1.y += wA.y * bf2f(u1.y);
        a1.z += wA.y * bf2f(u1.z); a1.w += wA.y * bf2f(u1.w);
        a2.x += wA.z * bf2f(u2.x); a2.y += wA.z * bf2f(u2.y);
        a2.z += wA.z * bf2f(u2.z); a2.w += wA.z * bf2f(u2.w);
        a3.x += wA.w * bf2f(u3.x); a3.y += wA.w * bf2f(u3.y);
        a3.z += wA.w * bf2f(u3.z); a3.w += wA.w * bf2f(u3.w);
        k += 4;
    }
    for (; k < end; ++k) {
        int so = srcs[k];
        float w = wp[k];
        ushort4 u = *(const ushort4*)(hbase + so);
        sw0 += w;
        a0.x += w * bf2f(u.x); a0.y += w * bf2f(u.y);
        a0.z += w * bf2f(u.z); a0.w += w * bf2f(u.w);
    }
    float4 acc = make_float4(a0.x + a1.x + a2.x + a3.x,
                             a0.y + a1.y + a2.y + a3.y,
                             a0.z + a1.z + a2.z + a3.z,
                             a0.w + a1.w + a2.w + a3.w);
    float inv = 1.f / (sw0 + sw1 + sw2 + sw3 + 1e-16f);
    float4 b = *(const float4*)&bias[f];
    float4 o;
    o.x = fmaxf(acc.x * inv + b.x, 0.f);
    o.y = fmaxf(acc.y * inv + b.y, 0.f);
    o.z = fmaxf(acc.z * inv + b.z, 0.f);
    o.w = fmaxf(acc.w * inv + b.w, 0.f);
    *(float4*)&out[(size_t)n * HF + f] = o;
}

extern "C" void kernel_launch(void* const* d_in, const int* in_sizes, int n_in,
                              void* d_out, int out_size, void* d_ws, size_t ws_size,
                              hipStream_t stream)
{
    const float* x    = (const float*)d_in[0];
    const float* W    = (const float*)d_in[1];
    const float* atts = (const float*)d_in[2];
    const float* attd = (const float*)d_in[3];
    const float* bias = (const float*)d_in[4];
    const int*   ei   = (const int*)d_in[5];
    float* out = (float*)d_out;

    // ws (int units): hb[6.4M] | WbT[32768] | a_src[200000] | a_dst[200000]
    //   | cnt[50000] | cur[50000] | off[50004] | srcs[850048] | blksum[64]
    //   | wT[4*850048]   (~45 MB); srcs and wT 16B-aligned by construction.
    unsigned short* hb  = (unsigned short*)d_ws;
    unsigned short* WbT = hb + (size_t)NN * HF;
    float* a_src = (float*)(WbT + 256 * 256);
    float* a_dst = a_src + (size_t)NN * 4;
    int*   cnt   = (int*)(a_dst + (size_t)NN * 4);
    int*   cur   = cnt + NN;
    int*   off   = cur + NN;
    int*   srcs  = off + NN + 4;                 // pad keeps 16B alignment
    int*   blksum = srcs + WP;
    float* wT    = (float*)(blksum + 64);

    hipMemsetAsync(cnt, 0, NN * sizeof(int), stream);

    prep<<<256 + (ET + 255) / 256, 256, 0, stream>>>(W, WbT, ei, cnt);
    gemm_mfma<<<(NN + 63) / 64, 256, 0, stream>>>(x, WbT, atts, attd, hb, a_src, a_dst);
    scan_local<<<49, 256, 0, stream>>>(cnt, off, blksum);
    add_off<<<49, 256, 0, stream>>>(off, cur, blksum);
    scatter_edges<<<(ET + 255) / 256, 256, 0, stream>>>(ei, a_src, a_dst, cur, srcs, wT);
    gather_agg<<<(NN * 64 + 255) / 256, 256, 0, stream>>>(srcs, wT, off, hb, bias, out);
}

// Round 7
// 195.666 us; speedup vs baseline: 1.1451x; 1.1451x over previous
//
#include <hip/hip_runtime.h>

// GATConv forward on MI355X — round 7.
// vs r6: scatter payload packed into ONE 16B record {so, w as 4xbf16} ->
// exactly 1 random cache line touched per edge (r5: 2, r6: 5). Record array
// 13.6MB. Gather unpacks w[hd] with 3 VALU ops; structure otherwise r5's.

#define NN 50000      // nodes
#define NE 800000     // real edges
#define ET 850000     // edges + self loops
#define KF 256        // IN_F
#define HF 256        // HEADS*OUT_F
#define HROW 512      // bytes per hb row (256 * bf16)

typedef __attribute__((ext_vector_type(8))) short bf16x8;
typedef __attribute__((ext_vector_type(4))) float f32x4;

static __device__ __forceinline__ unsigned short f2bf(float f) {
    unsigned u = __builtin_bit_cast(unsigned, f);
    u += 0x7fffu + ((u >> 16) & 1u);            // round-to-nearest-even
    return (unsigned short)(u >> 16);
}
static __device__ __forceinline__ float bf2f(unsigned short s) {
    return __builtin_bit_cast(float, ((unsigned)s) << 16);
}

// ------------- prep: transpose W (blocks 0..255) + count edges (rest) -------
__global__ __launch_bounds__(256) void prep(
    const float* __restrict__ W, unsigned short* __restrict__ WbT,
    const int* __restrict__ ei, int* __restrict__ cnt)
{
    const int b = blockIdx.x;
    if (b < 256) {
        int g = b * 256 + threadIdx.x;
        int n = g >> 8, k = g & 255;
        WbT[n * 256 + k] = f2bf(W[k * 256 + n]);
    } else {
        int e = (b - 256) * 256 + threadIdx.x;
        if (e < ET) {
            int d = (e < NE) ? ei[NE + e] : e - NE;
            atomicAdd(&cnt[d], 1);
        }
    }
}

// ------------- GEMM + fused attention dots ----------------------------------
__global__ __launch_bounds__(256) void gemm_mfma(
    const float* __restrict__ x, const unsigned short* __restrict__ WbT,
    const float* __restrict__ att_s, const float* __restrict__ att_d,
    unsigned short* __restrict__ hb, float* __restrict__ a_src,
    float* __restrict__ a_dst)
{
    __shared__ unsigned short As[64 * 256];      // [row][k], 16B slots XOR-swizzled
    const int tid  = threadIdx.x;
    const int row0 = blockIdx.x * 64;
    {
        const int row = tid >> 2, s = tid & 3;
        const int grow = row0 + row;
        #pragma unroll
        for (int kc = 0; kc < 8; ++kc) {
            int slot = kc * 4 + s;               // 16B slot (k = slot*8..+7)
            float4 p = make_float4(0.f,0.f,0.f,0.f), q = p;
            if (grow < NN) {
                const float* src = &x[(size_t)grow * KF + slot * 8];
                p = *(const float4*)src;
                q = *(const float4*)(src + 4);
            }
            bf16x8 v;
            v[0]=(short)f2bf(p.x); v[1]=(short)f2bf(p.y);
            v[2]=(short)f2bf(p.z); v[3]=(short)f2bf(p.w);
            v[4]=(short)f2bf(q.x); v[5]=(short)f2bf(q.y);
            v[6]=(short)f2bf(q.z); v[7]=(short)f2bf(q.w);
            *(bf16x8*)&As[row * 256 + ((slot ^ (row & 7)) * 8)] = v;
        }
    }
    __syncthreads();

    const int wave = tid >> 6, lane = tid & 63;
    const int r = lane & 15, g = lane >> 4;
    const int c0 = wave * 64;
    f32x4 acc[4][4] = {};
    #pragma unroll 2
    for (int kstep = 0; kstep < 8; ++kstep) {
        const int k0 = kstep * 32;
        bf16x8 af[4], bfr[4];
        #pragma unroll
        for (int mf = 0; mf < 4; ++mf) {
            int arow = mf * 16 + r;
            int slot = (kstep * 4 + g) ^ (arow & 7);
            af[mf] = *(const bf16x8*)&As[arow * 256 + slot * 8];
        }
        #pragma unroll
        for (int nf = 0; nf < 4; ++nf) {
            int col = c0 + nf * 16 + r;
            bfr[nf] = *(const bf16x8*)&WbT[(size_t)col * 256 + k0 + g * 8];
        }
        #pragma unroll
        for (int mf = 0; mf < 4; ++mf)
            #pragma unroll
            for (int nf = 0; nf < 4; ++nf)
                acc[mf][nf] = __builtin_amdgcn_mfma_f32_16x16x32_bf16(
                    af[mf], bfr[nf], acc[mf][nf], 0, 0, 0);
    }
    // ---- fused attention epilogue (head == wave) ---------------------------
    {
        float as[4], ad[4];
        #pragma unroll
        for (int nf = 0; nf < 4; ++nf) {
            as[nf] = att_s[c0 + nf * 16 + r];
            ad[nf] = att_d[c0 + nf * 16 + r];
        }
        #pragma unroll
        for (int mf = 0; mf < 4; ++mf) {
            #pragma unroll
            for (int rr = 0; rr < 4; ++rr) {
                float ps = acc[mf][0][rr]*as[0] + acc[mf][1][rr]*as[1]
                         + acc[mf][2][rr]*as[2] + acc[mf][3][rr]*as[3];
                float pd = acc[mf][0][rr]*ad[0] + acc[mf][1][rr]*ad[1]
                         + acc[mf][2][rr]*ad[2] + acc[mf][3][rr]*ad[3];
                #pragma unroll
                for (int m = 1; m < 16; m <<= 1) {
                    ps += __shfl_xor(ps, m);
                    pd += __shfl_xor(pd, m);
                }
                if (r == 0) {
                    int orow = row0 + mf * 16 + g * 4 + rr;
                    if (orow < NN) {
                        a_src[orow * 4 + wave] = ps;
                        a_dst[orow * 4 + wave] = pd;
                    }
                }
            }
        }
    }
    // ---- hb store ----------------------------------------------------------
    #pragma unroll
    for (int mf = 0; mf < 4; ++mf) {
        #pragma unroll
        for (int rr = 0; rr < 4; ++rr) {
            int orow = row0 + mf * 16 + g * 4 + rr;
            if (orow < NN) {
                #pragma unroll
                for (int nf = 0; nf < 4; ++nf)
                    hb[(size_t)orow * HF + c0 + nf * 16 + r] = f2bf(acc[mf][nf][rr]);
            }
        }
    }
}

// ------------- hierarchical scan --------------------------------------------
__global__ __launch_bounds__(256) void scan_local(
    const int* __restrict__ cnt, int* __restrict__ off, int* __restrict__ blksum)
{
    __shared__ int part[256];
    const int t = threadIdx.x;
    const int base = blockIdx.x * 1024 + t * 4;
    int4 v = make_int4(0, 0, 0, 0);
    if (base < NN) v = *(const int4*)&cnt[base];
    int s0 = v.x, s1 = s0 + v.y, s2 = s1 + v.z, s3 = s2 + v.w;
    part[t] = s3;
    __syncthreads();
    #pragma unroll
    for (int ofs = 1; ofs < 256; ofs <<= 1) {
        int u = (t >= ofs) ? part[t - ofs] : 0;
        __syncthreads();
        part[t] += u;
        __syncthreads();
    }
    int excl = part[t] - s3;
    if (base < NN)
        *(int4*)&off[base] = make_int4(excl, excl + s0, excl + s1, excl + s2);
    if (t == 255) blksum[blockIdx.x] = part[255];
}

// fused: each block re-scans the 49 block sums in wave 0, then adds.
__global__ __launch_bounds__(256) void add_off(
    int* __restrict__ off, int* __restrict__ cur, const int* __restrict__ blksum)
{
    __shared__ int s_bo;
    if (threadIdx.x < 64) {
        int t = threadIdx.x;
        int v = (t < 49) ? blksum[t] : 0;
        int incl = v;
        #pragma unroll
        for (int d = 1; d < 64; d <<= 1) {
            int u = __shfl_up(incl, d);
            if (t >= d) incl += u;
        }
        if (t == (int)blockIdx.x) s_bo = incl - v;   // exclusive prefix
    }
    __syncthreads();
    const int bo = s_bo;
    const int base = blockIdx.x * 1024 + threadIdx.x * 4;
    if (base < NN) {
        int4 o = *(const int4*)&off[base];
        o.x += bo; o.y += bo; o.z += bo; o.w += bo;
        *(int4*)&off[base] = o;
        *(int4*)&cur[base] = o;
    }
    if (blockIdx.x == 0 && threadIdx.x == 0) off[NN] = ET;
}

// ------------- scatter: one 16B record per edge {so, w packed 4xbf16} -------
__global__ __launch_bounds__(256) void scatter_edges(
    const int* __restrict__ ei, const float* __restrict__ a_src,
    const float* __restrict__ a_dst, int* __restrict__ cur,
    uint4* __restrict__ recs)
{
    int e = blockIdx.x * 256 + threadIdx.x;
    if (e >= ET) return;
    int s, d;
    if (e < NE) { s = ei[e]; d = ei[NE + e]; }
    else        { s = e - NE; d = s; }
    float4 av = *(const float4*)&a_src[s * 4];
    float4 bv = *(const float4*)&a_dst[d * 4];
    float4 ev;
    ev.x = av.x + bv.x; ev.y = av.y + bv.y;
    ev.z = av.z + bv.z; ev.w = av.w + bv.w;
    ev.x = ev.x > 0.f ? ev.x : 0.2f * ev.x;
    ev.y = ev.y > 0.f ? ev.y : 0.2f * ev.y;
    ev.z = ev.z > 0.f ? ev.z : 0.2f * ev.z;
    ev.w = ev.w > 0.f ? ev.w : 0.2f * ev.w;
    ev.x = __expf(ev.x); ev.y = __expf(ev.y);
    ev.z = __expf(ev.z); ev.w = __expf(ev.w);
    uint4 rec;
    rec.x = (unsigned)(s * HROW);                               // byte offset
    rec.y = (unsigned)f2bf(ev.x) | ((unsigned)f2bf(ev.y) << 16);
    rec.z = (unsigned)f2bf(ev.z) | ((unsigned)f2bf(ev.w) << 16);
    rec.w = 0;
    int pos = atomicAdd(&cur[d], 1);
    recs[pos] = rec;                                            // 1 line/edge
}

// per-lane weight extraction: head hd from packed rec dwords
static __device__ __forceinline__ float wext(unsigned y, unsigned z, int hd) {
    unsigned dw = (hd & 2) ? z : y;
    dw = (hd & 1) ? (dw & 0xffff0000u) : (dw << 16);
    return __builtin_bit_cast(float, dw);
}

// ------------- gather aggregation: one wave per dst node --------------------
// out[n] = relu( (sum w_e * h[s_e]) / (sum w_e + eps) + bias )
__global__ __launch_bounds__(256) void gather_agg(
    const uint4* __restrict__ recs, const int* __restrict__ off,
    const unsigned short* __restrict__ hb, const float* __restrict__ bias,
    float* __restrict__ out)
{
    int n    = (blockIdx.x * 256 + threadIdx.x) >> 6;
    int lane = threadIdx.x & 63;
    if (n >= NN) return;
    const int beg = off[n], end = off[n + 1];
    const int hd  = lane >> 4;
    const int f   = lane << 2;
    const char* hbase = (const char*)hb + (lane << 3);
    float4 a0 = make_float4(0.f,0.f,0.f,0.f), a1 = a0;
    float sw0 = 0.f, sw1 = 0.f;
    int k = beg;
    for (; k + 3 < end; k += 4) {
        uint4 r0 = recs[k],     r1 = recs[k + 1];
        uint4 r2 = recs[k + 2], r3 = recs[k + 3];
        ushort4 u0 = *(const ushort4*)(hbase + r0.x);
        ushort4 u1 = *(const ushort4*)(hbase + r1.x);
        ushort4 u2 = *(const ushort4*)(hbase + r2.x);
        ushort4 u3 = *(const ushort4*)(hbase + r3.x);
        float w0 = wext(r0.y, r0.z, hd), w1 = wext(r1.y, r1.z, hd);
        float w2 = wext(r2.y, r2.z, hd), w3 = wext(r3.y, r3.z, hd);
        sw0 += w0 + w2; sw1 += w1 + w3;
        a0.x += w0 * bf2f(u0.x) + w2 * bf2f(u2.x);
        a0.y += w0 * bf2f(u0.y) + w2 * bf2f(u2.y);
        a0.z += w0 * bf2f(u0.z) + w2 * bf2f(u2.z);
        a0.w += w0 * bf2f(u0.w) + w2 * bf2f(u2.w);
        a1.x += w1 * bf2f(u1.x) + w3 * bf2f(u3.x);
        a1.y += w1 * bf2f(u1.y) + w3 * bf2f(u3.y);
        a1.z += w1 * bf2f(u1.z) + w3 * bf2f(u3.z);
        a1.w += w1 * bf2f(u1.w) + w3 * bf2f(u3.w);
    }
    for (; k < end; ++k) {
        uint4 r0 = recs[k];
        ushort4 u0 = *(const ushort4*)(hbase + r0.x);
        float w0 = wext(r0.y, r0.z, hd);
        sw0 += w0;
        a0.x += w0 * bf2f(u0.x); a0.y += w0 * bf2f(u0.y);
        a0.z += w0 * bf2f(u0.z); a0.w += w0 * bf2f(u0.w);
    }
    float4 acc = make_float4(a0.x + a1.x, a0.y + a1.y,
                             a0.z + a1.z, a0.w + a1.w);
    float inv = 1.f / (sw0 + sw1 + 1e-16f);
    float4 b = *(const float4*)&bias[f];
    float4 o;
    o.x = fmaxf(acc.x * inv + b.x, 0.f);
    o.y = fmaxf(acc.y * inv + b.y, 0.f);
    o.z = fmaxf(acc.z * inv + b.z, 0.f);
    o.w = fmaxf(acc.w * inv + b.w, 0.f);
    *(float4*)&out[(size_t)n * HF + f] = o;
}

extern "C" void kernel_launch(void* const* d_in, const int* in_sizes, int n_in,
                              void* d_out, int out_size, void* d_ws, size_t ws_size,
                              hipStream_t stream)
{
    const float* x    = (const float*)d_in[0];
    const float* W    = (const float*)d_in[1];
    const float* atts = (const float*)d_in[2];
    const float* attd = (const float*)d_in[3];
    const float* bias = (const float*)d_in[4];
    const int*   ei   = (const int*)d_in[5];
    float* out = (float*)d_out;

    // ws: hb[NN*256]bf16 | WbT[64K]bf16 | recs[ET]uint4 | a_src[NN*4]
    //     | a_dst[NN*4] | cnt[NN] | cur[NN] | off[NN+1] | blksum[64]  (~41 MB)
    unsigned short* hb  = (unsigned short*)d_ws;
    unsigned short* WbT = hb + (size_t)NN * HF;
    uint4* recs  = (uint4*)(WbT + 256 * 256);    // 16B aligned (offset 25.73MB, %16==0)
    float* a_src = (float*)(recs + ET);
    float* a_dst = a_src + (size_t)NN * 4;
    int*   cnt   = (int*)(a_dst + (size_t)NN * 4);
    int*   cur   = cnt + NN;
    int*   off   = cur + NN;
    int*   blksum = off + NN + 4;

    hipMemsetAsync(cnt, 0, NN * sizeof(int), stream);

    prep<<<256 + (ET + 255) / 256, 256, 0, stream>>>(W, WbT, ei, cnt);
    gemm_mfma<<<(NN + 63) / 64, 256, 0, stream>>>(x, WbT, atts, attd, hb, a_src, a_dst);
    scan_local<<<49, 256, 0, stream>>>(cnt, off, blksum);
    add_off<<<49, 256, 0, stream>>>(off, cur, blksum);
    scatter_edges<<<(ET + 255) / 256, 256, 0, stream>>>(ei, a_src, a_dst, cur, recs);
    gather_agg<<<(NN * 64 + 255) / 256, 256, 0, stream>>>(recs, off, hb, bias, out);
}

// Round 9
// 195.300 us; speedup vs baseline: 1.1472x; 1.0019x over previous
//
#include <hip/hip_runtime.h>

// GATConv forward on MI355X — round 9 (r8 compile fix: nontemporal builtins
// need native ext_vector types, not HIP_vector_type float4).
// vs r7: gather (1) stages records chunk-wise in LDS via one lane-parallel
// load per 64 edges (record reads move to the idle DS pipe; L2 transactions
// per edge 5->4); (2) unroll x8, 4 accumulator chains (8 h-loads in flight);
// (3) nontemporal out stores (don't evict h from L2); gemm x loads nt.

#define NN 50000      // nodes
#define NE 800000     // real edges
#define ET 850000     // edges + self loops
#define KF 256        // IN_F
#define HF 256        // HEADS*OUT_F
#define HROW 512      // bytes per hb row (256 * bf16)

typedef __attribute__((ext_vector_type(8))) short bf16x8;
typedef __attribute__((ext_vector_type(4))) float f32x4;

static __device__ __forceinline__ unsigned short f2bf(float f) {
    unsigned u = __builtin_bit_cast(unsigned, f);
    u += 0x7fffu + ((u >> 16) & 1u);            // round-to-nearest-even
    return (unsigned short)(u >> 16);
}
static __device__ __forceinline__ float bf2f(unsigned short s) {
    return __builtin_bit_cast(float, ((unsigned)s) << 16);
}

// ------------- prep: transpose W (blocks 0..255) + count edges (rest) -------
__global__ __launch_bounds__(256) void prep(
    const float* __restrict__ W, unsigned short* __restrict__ WbT,
    const int* __restrict__ ei, int* __restrict__ cnt)
{
    const int b = blockIdx.x;
    if (b < 256) {
        int g = b * 256 + threadIdx.x;
        int n = g >> 8, k = g & 255;
        WbT[n * 256 + k] = f2bf(W[k * 256 + n]);
    } else {
        int e = (b - 256) * 256 + threadIdx.x;
        if (e < ET) {
            int d = (e < NE) ? ei[NE + e] : e - NE;
            atomicAdd(&cnt[d], 1);
        }
    }
}

// ------------- GEMM + fused attention dots ----------------------------------
__global__ __launch_bounds__(256) void gemm_mfma(
    const float* __restrict__ x, const unsigned short* __restrict__ WbT,
    const float* __restrict__ att_s, const float* __restrict__ att_d,
    unsigned short* __restrict__ hb, float* __restrict__ a_src,
    float* __restrict__ a_dst)
{
    __shared__ unsigned short As[64 * 256];      // [row][k], 16B slots XOR-swizzled
    const int tid  = threadIdx.x;
    const int row0 = blockIdx.x * 64;
    {
        const int row = tid >> 2, s = tid & 3;
        const int grow = row0 + row;
        #pragma unroll
        for (int kc = 0; kc < 8; ++kc) {
            int slot = kc * 4 + s;               // 16B slot (k = slot*8..+7)
            f32x4 p = (f32x4)(0.f), q = (f32x4)(0.f);
            if (grow < NN) {
                const f32x4* src = (const f32x4*)&x[(size_t)grow * KF + slot * 8];
                p = __builtin_nontemporal_load(src);
                q = __builtin_nontemporal_load(src + 1);
            }
            bf16x8 v;
            v[0]=(short)f2bf(p.x); v[1]=(short)f2bf(p.y);
            v[2]=(short)f2bf(p.z); v[3]=(short)f2bf(p.w);
            v[4]=(short)f2bf(q.x); v[5]=(short)f2bf(q.y);
            v[6]=(short)f2bf(q.z); v[7]=(short)f2bf(q.w);
            *(bf16x8*)&As[row * 256 + ((slot ^ (row & 7)) * 8)] = v;
        }
    }
    __syncthreads();

    const int wave = tid >> 6, lane = tid & 63;
    const int r = lane & 15, g = lane >> 4;
    const int c0 = wave * 64;
    f32x4 acc[4][4] = {};
    #pragma unroll 2
    for (int kstep = 0; kstep < 8; ++kstep) {
        const int k0 = kstep * 32;
        bf16x8 af[4], bfr[4];
        #pragma unroll
        for (int mf = 0; mf < 4; ++mf) {
            int arow = mf * 16 + r;
            int slot = (kstep * 4 + g) ^ (arow & 7);
            af[mf] = *(const bf16x8*)&As[arow * 256 + slot * 8];
        }
        #pragma unroll
        for (int nf = 0; nf < 4; ++nf) {
            int col = c0 + nf * 16 + r;
            bfr[nf] = *(const bf16x8*)&WbT[(size_t)col * 256 + k0 + g * 8];
        }
        #pragma unroll
        for (int mf = 0; mf < 4; ++mf)
            #pragma unroll
            for (int nf = 0; nf < 4; ++nf)
                acc[mf][nf] = __builtin_amdgcn_mfma_f32_16x16x32_bf16(
                    af[mf], bfr[nf], acc[mf][nf], 0, 0, 0);
    }
    // ---- fused attention epilogue (head == wave) ---------------------------
    {
        float as[4], ad[4];
        #pragma unroll
        for (int nf = 0; nf < 4; ++nf) {
            as[nf] = att_s[c0 + nf * 16 + r];
            ad[nf] = att_d[c0 + nf * 16 + r];
        }
        #pragma unroll
        for (int mf = 0; mf < 4; ++mf) {
            #pragma unroll
            for (int rr = 0; rr < 4; ++rr) {
                float ps = acc[mf][0][rr]*as[0] + acc[mf][1][rr]*as[1]
                         + acc[mf][2][rr]*as[2] + acc[mf][3][rr]*as[3];
                float pd = acc[mf][0][rr]*ad[0] + acc[mf][1][rr]*ad[1]
                         + acc[mf][2][rr]*ad[2] + acc[mf][3][rr]*ad[3];
                #pragma unroll
                for (int m = 1; m < 16; m <<= 1) {
                    ps += __shfl_xor(ps, m);
                    pd += __shfl_xor(pd, m);
                }
                if (r == 0) {
                    int orow = row0 + mf * 16 + g * 4 + rr;
                    if (orow < NN) {
                        a_src[orow * 4 + wave] = ps;
                        a_dst[orow * 4 + wave] = pd;
                    }
                }
            }
        }
    }
    // ---- hb store ----------------------------------------------------------
    #pragma unroll
    for (int mf = 0; mf < 4; ++mf) {
        #pragma unroll
        for (int rr = 0; rr < 4; ++rr) {
            int orow = row0 + mf * 16 + g * 4 + rr;
            if (orow < NN) {
                #pragma unroll
                for (int nf = 0; nf < 4; ++nf)
                    hb[(size_t)orow * HF + c0 + nf * 16 + r] = f2bf(acc[mf][nf][rr]);
            }
        }
    }
}

// ------------- hierarchical scan --------------------------------------------
__global__ __launch_bounds__(256) void scan_local(
    const int* __restrict__ cnt, int* __restrict__ off, int* __restrict__ blksum)
{
    __shared__ int part[256];
    const int t = threadIdx.x;
    const int base = blockIdx.x * 1024 + t * 4;
    int4 v = make_int4(0, 0, 0, 0);
    if (base < NN) v = *(const int4*)&cnt[base];
    int s0 = v.x, s1 = s0 + v.y, s2 = s1 + v.z, s3 = s2 + v.w;
    part[t] = s3;
    __syncthreads();
    #pragma unroll
    for (int ofs = 1; ofs < 256; ofs <<= 1) {
        int u = (t >= ofs) ? part[t - ofs] : 0;
        __syncthreads();
        part[t] += u;
        __syncthreads();
    }
    int excl = part[t] - s3;
    if (base < NN)
        *(int4*)&off[base] = make_int4(excl, excl + s0, excl + s1, excl + s2);
    if (t == 255) blksum[blockIdx.x] = part[255];
}

// fused: each block re-scans the 49 block sums in wave 0, then adds.
__global__ __launch_bounds__(256) void add_off(
    int* __restrict__ off, int* __restrict__ cur, const int* __restrict__ blksum)
{
    __shared__ int s_bo;
    if (threadIdx.x < 64) {
        int t = threadIdx.x;
        int v = (t < 49) ? blksum[t] : 0;
        int incl = v;
        #pragma unroll
        for (int d = 1; d < 64; d <<= 1) {
            int u = __shfl_up(incl, d);
            if (t >= d) incl += u;
        }
        if (t == (int)blockIdx.x) s_bo = incl - v;   // exclusive prefix
    }
    __syncthreads();
    const int bo = s_bo;
    const int base = blockIdx.x * 1024 + threadIdx.x * 4;
    if (base < NN) {
        int4 o = *(const int4*)&off[base];
        o.x += bo; o.y += bo; o.z += bo; o.w += bo;
        *(int4*)&off[base] = o;
        *(int4*)&cur[base] = o;
    }
    if (blockIdx.x == 0 && threadIdx.x == 0) off[NN] = ET;
}

// ------------- scatter: one 16B record per edge {so, w packed 4xbf16} -------
__global__ __launch_bounds__(256) void scatter_edges(
    const int* __restrict__ ei, const float* __restrict__ a_src,
    const float* __restrict__ a_dst, int* __restrict__ cur,
    uint4* __restrict__ recs)
{
    int e = blockIdx.x * 256 + threadIdx.x;
    if (e >= ET) return;
    int s, d;
    if (e < NE) { s = ei[e]; d = ei[NE + e]; }
    else        { s = e - NE; d = s; }
    float4 av = *(const float4*)&a_src[s * 4];
    float4 bv = *(const float4*)&a_dst[d * 4];
    float4 ev;
    ev.x = av.x + bv.x; ev.y = av.y + bv.y;
    ev.z = av.z + bv.z; ev.w = av.w + bv.w;
    ev.x = ev.x > 0.f ? ev.x : 0.2f * ev.x;
    ev.y = ev.y > 0.f ? ev.y : 0.2f * ev.y;
    ev.z = ev.z > 0.f ? ev.z : 0.2f * ev.z;
    ev.w = ev.w > 0.f ? ev.w : 0.2f * ev.w;
    ev.x = __expf(ev.x); ev.y = __expf(ev.y);
    ev.z = __expf(ev.z); ev.w = __expf(ev.w);
    uint4 rec;
    rec.x = (unsigned)(s * HROW);                               // byte offset
    rec.y = (unsigned)f2bf(ev.x) | ((unsigned)f2bf(ev.y) << 16);
    rec.z = (unsigned)f2bf(ev.z) | ((unsigned)f2bf(ev.w) << 16);
    rec.w = 0;
    int pos = atomicAdd(&cur[d], 1);
    recs[pos] = rec;                                            // 1 line/edge
}

// per-lane weight extraction: head hd from packed rec dwords
static __device__ __forceinline__ float wext(unsigned y, unsigned z, int hd) {
    unsigned dw = (hd & 2) ? z : y;
    dw = (hd & 1) ? (dw & 0xffff0000u) : (dw << 16);
    return __builtin_bit_cast(float, dw);
}

// ------------- gather aggregation: one wave per dst node --------------------
// Records staged chunk-wise (64/chunk) into LDS by one lane-parallel load;
// inner loop reads them via broadcast ds_read (DS pipe), h rows via VMEM.
__global__ __launch_bounds__(256) void gather_agg(
    const uint4* __restrict__ recs, const int* __restrict__ off,
    const unsigned short* __restrict__ hb, const float* __restrict__ bias,
    float* __restrict__ out)
{
    __shared__ uint4 rbuf[4][64];                // 4 KB: 1 KB per wave
    int n    = (blockIdx.x * 256 + threadIdx.x) >> 6;
    int lane = threadIdx.x & 63;
    if (n >= NN) return;
    const int wv  = threadIdx.x >> 6;
    const int beg = off[n], end = off[n + 1];
    const int hd  = lane >> 4;
    const int f   = lane << 2;
    const char* hbase = (const char*)hb + (lane << 3);
    float4 a0 = make_float4(0.f,0.f,0.f,0.f), a1 = a0, a2 = a0, a3 = a0;
    float sw0 = 0.f, sw1 = 0.f, sw2 = 0.f, sw3 = 0.f;

    for (int base = beg; base < end; base += 64) {
        int m = end - base; if (m > 64) m = 64;
        if (lane < m) rbuf[wv][lane] = recs[base + lane];
        int j = 0;
        for (; j + 7 < m; j += 8) {
            uint4 r0 = rbuf[wv][j],     r1 = rbuf[wv][j + 1];
            uint4 r2 = rbuf[wv][j + 2], r3 = rbuf[wv][j + 3];
            uint4 r4 = rbuf[wv][j + 4], r5 = rbuf[wv][j + 5];
            uint4 r6 = rbuf[wv][j + 6], r7 = rbuf[wv][j + 7];
            ushort4 u0 = *(const ushort4*)(hbase + r0.x);
            ushort4 u1 = *(const ushort4*)(hbase + r1.x);
            ushort4 u2 = *(const ushort4*)(hbase + r2.x);
            ushort4 u3 = *(const ushort4*)(hbase + r3.x);
            ushort4 u4 = *(const ushort4*)(hbase + r4.x);
            ushort4 u5 = *(const ushort4*)(hbase + r5.x);
            ushort4 u6 = *(const ushort4*)(hbase + r6.x);
            ushort4 u7 = *(const ushort4*)(hbase + r7.x);
            float w0 = wext(r0.y, r0.z, hd), w1 = wext(r1.y, r1.z, hd);
            float w2 = wext(r2.y, r2.z, hd), w3 = wext(r3.y, r3.z, hd);
            float w4 = wext(r4.y, r4.z, hd), w5 = wext(r5.y, r5.z, hd);
            float w6 = wext(r6.y, r6.z, hd), w7 = wext(r7.y, r7.z, hd);
            sw0 += w0 + w4; sw1 += w1 + w5; sw2 += w2 + w6; sw3 += w3 + w7;
            a0.x += w0 * bf2f(u0.x) + w4 * bf2f(u4.x);
            a0.y += w0 * bf2f(u0.y) + w4 * bf2f(u4.y);
            a0.z += w0 * bf2f(u0.z) + w4 * bf2f(u4.z);
            a0.w += w0 * bf2f(u0.w) + w4 * bf2f(u4.w);
            a1.x += w1 * bf2f(u1.x) + w5 * bf2f(u5.x);
            a1.y += w1 * bf2f(u1.y) + w5 * bf2f(u5.y);
            a1.z += w1 * bf2f(u1.z) + w5 * bf2f(u5.z);
            a1.w += w1 * bf2f(u1.w) + w5 * bf2f(u5.w);
            a2.x += w2 * bf2f(u2.x) + w6 * bf2f(u6.x);
            a2.y += w2 * bf2f(u2.y) + w6 * bf2f(u6.y);
            a2.z += w2 * bf2f(u2.z) + w6 * bf2f(u6.z);
            a2.w += w2 * bf2f(u2.w) + w6 * bf2f(u6.w);
            a3.x += w3 * bf2f(u3.x) + w7 * bf2f(u7.x);
            a3.y += w3 * bf2f(u3.y) + w7 * bf2f(u7.y);
            a3.z += w3 * bf2f(u3.z) + w7 * bf2f(u7.z);
            a3.w += w3 * bf2f(u3.w) + w7 * bf2f(u7.w);
        }
        if (j + 3 < m) {
            uint4 r0 = rbuf[wv][j],     r1 = rbuf[wv][j + 1];
            uint4 r2 = rbuf[wv][j + 2], r3 = rbuf[wv][j + 3];
            ushort4 u0 = *(const ushort4*)(hbase + r0.x);
            ushort4 u1 = *(const ushort4*)(hbase + r1.x);
            ushort4 u2 = *(const ushort4*)(hbase + r2.x);
            ushort4 u3 = *(const ushort4*)(hbase + r3.x);
            float w0 = wext(r0.y, r0.z, hd), w1 = wext(r1.y, r1.z, hd);
            float w2 = wext(r2.y, r2.z, hd), w3 = wext(r3.y, r3.z, hd);
            sw0 += w0; sw1 += w1; sw2 += w2; sw3 += w3;
            a0.x += w0 * bf2f(u0.x); a0.y += w0 * bf2f(u0.y);
            a0.z += w0 * bf2f(u0.z); a0.w += w0 * bf2f(u0.w);
            a1.x += w1 * bf2f(u1.x); a1.y += w1 * bf2f(u1.y);
            a1.z += w1 * bf2f(u1.z); a1.w += w1 * bf2f(u1.w);
            a2.x += w2 * bf2f(u2.x); a2.y += w2 * bf2f(u2.y);
            a2.z += w2 * bf2f(u2.z); a2.w += w2 * bf2f(u2.w);
            a3.x += w3 * bf2f(u3.x); a3.y += w3 * bf2f(u3.y);
            a3.z += w3 * bf2f(u3.z); a3.w += w3 * bf2f(u3.w);
            j += 4;
        }
        for (; j < m; ++j) {
            uint4 r0 = rbuf[wv][j];
            ushort4 u0 = *(const ushort4*)(hbase + r0.x);
            float w0 = wext(r0.y, r0.z, hd);
            sw0 += w0;
            a0.x += w0 * bf2f(u0.x); a0.y += w0 * bf2f(u0.y);
            a0.z += w0 * bf2f(u0.z); a0.w += w0 * bf2f(u0.w);
        }
    }
    float4 acc = make_float4(a0.x + a1.x + a2.x + a3.x,
                             a0.y + a1.y + a2.y + a3.y,
                             a0.z + a1.z + a2.z + a3.z,
                             a0.w + a1.w + a2.w + a3.w);
    float inv = 1.f / (sw0 + sw1 + sw2 + sw3 + 1e-16f);
    float4 b = *(const float4*)&bias[f];
    f32x4 o;
    o.x = fmaxf(acc.x * inv + b.x, 0.f);
    o.y = fmaxf(acc.y * inv + b.y, 0.f);
    o.z = fmaxf(acc.z * inv + b.z, 0.f);
    o.w = fmaxf(acc.w * inv + b.w, 0.f);
    __builtin_nontemporal_store(o, (f32x4*)&out[(size_t)n * HF + f]);
}

extern "C" void kernel_launch(void* const* d_in, const int* in_sizes, int n_in,
                              void* d_out, int out_size, void* d_ws, size_t ws_size,
                              hipStream_t stream)
{
    const float* x    = (const float*)d_in[0];
    const float* W    = (const float*)d_in[1];
    const float* atts = (const float*)d_in[2];
    const float* attd = (const float*)d_in[3];
    const float* bias = (const float*)d_in[4];
    const int*   ei   = (const int*)d_in[5];
    float* out = (float*)d_out;

    // ws: hb[NN*256]bf16 | WbT[64K]bf16 | recs[ET]uint4 | a_src[NN*4]
    //     | a_dst[NN*4] | cnt[NN] | cur[NN] | off[NN+1] | blksum[64]  (~41 MB)
    unsigned short* hb  = (unsigned short*)d_ws;
    unsigned short* WbT = hb + (size_t)NN * HF;
    uint4* recs  = (uint4*)(WbT + 256 * 256);
    float* a_src = (float*)(recs + ET);
    float* a_dst = a_src + (size_t)NN * 4;
    int*   cnt   = (int*)(a_dst + (size_t)NN * 4);
    int*   cur   = cnt + NN;
    int*   off   = cur + NN;
    int*   blksum = off + NN + 4;

    (void)hipMemsetAsync(cnt, 0, NN * sizeof(int), stream);

    prep<<<256 + (ET + 255) / 256, 256, 0, stream>>>(W, WbT, ei, cnt);
    gemm_mfma<<<(NN + 63) / 64, 256, 0, stream>>>(x, WbT, atts, attd, hb, a_src, a_dst);
    scan_local<<<49, 256, 0, stream>>>(cnt, off, blksum);
    add_off<<<49, 256, 0, stream>>>(off, cur, blksum);
    scatter_edges<<<(ET + 255) / 256, 256, 0, stream>>>(ei, a_src, a_dst, cur, recs);
    gather_agg<<<(NN * 64 + 255) / 256, 256, 0, stream>>>(recs, off, hb, bias, out);
}